// Round 4
// baseline (4065.247 us; speedup 1.0000x reference)
//
#include <hip/hip_runtime.h>
#include <cstddef>
#include <cstdint>

// Problem constants
#define B_     32
#define L_     4096
#define C_     512
#define WS_    64
#define SHIFT_ 32
#define NH_    8
#define DK_    64
#define HID_   2048
#define NW_    64   // L / WS

typedef __bf16 bf16x8 __attribute__((ext_vector_type(8)));
typedef float  f32x4  __attribute__((ext_vector_type(4)));

__device__ __forceinline__ float gelu_exact(float x) {
    return 0.5f * x * (1.0f + erff(x * 0.70710678118654752440f));
}

// fp32 -> bf16 bits, round-to-nearest-even (finite inputs only)
__device__ __forceinline__ unsigned short f2bf(float f) {
    unsigned u = __float_as_uint(f);
    u += 0x7FFFu + ((u >> 16) & 1u);
    return (unsigned short)(u >> 16);
}
__device__ __forceinline__ unsigned pack2(float a, float b) {
    return (unsigned)f2bf(a) | ((unsigned)f2bf(b) << 16);
}
__device__ __forceinline__ float b2f_lo(unsigned u) { return __uint_as_float(u << 16); }
__device__ __forceinline__ float b2f_hi(unsigned u) { return __uint_as_float(u & 0xFFFF0000u); }

// async global->LDS, 16B per lane. LDS base must be wave-uniform; HW adds lane*16.
__device__ __forceinline__ void gload_lds16(const void* g, void* l) {
    __builtin_amdgcn_global_load_lds(
        (const __attribute__((address_space(1))) void*)g,
        (__attribute__((address_space(3))) void*)l,
        16, 0, 0);
}

// ---------------------------------------------------------------------------
// fp32 -> bf16 conversion (weights). n4 = n/4.
// ---------------------------------------------------------------------------
__global__ __launch_bounds__(256)
void f2b_kernel(const float* __restrict__ in, unsigned short* __restrict__ out, int n4) {
    int i = blockIdx.x * blockDim.x + threadIdx.x;
    if (i >= n4) return;
    float4 v = ((const float4*)in)[i];
    ushort4 o;
    o.x = f2bf(v.x); o.y = f2bf(v.y); o.z = f2bf(v.z); o.w = f2bf(v.w);
    ((ushort4*)out)[i] = o;
}

// ---------------------------------------------------------------------------
// LayerNorm with optional roll, bf16 output:
//   y[b,l,:] = bf16( LN(x[b,(l+shift)%L,:]) * g + b )
// One wave per row of 512; block = 4 waves.
// ---------------------------------------------------------------------------
__global__ __launch_bounds__(256)
void ln_kernel(const float* __restrict__ x, const float* __restrict__ gamma,
               const float* __restrict__ beta, unsigned short* __restrict__ y, int shift) {
    const int wid  = threadIdx.x >> 6;
    const int lane = threadIdx.x & 63;
    const int row  = blockIdx.x * 4 + wid;        // output row in [0, B*L)
    const int b    = row >> 12;
    const int l    = row & (L_ - 1);
    const int lsrc = (l + shift) & (L_ - 1);
    const float* xr = x + ((size_t)((b << 12) + lsrc)) * C_ + lane * 8;

    float4 v0 = *(const float4*)(xr);
    float4 v1 = *(const float4*)(xr + 4);
    float s  = v0.x + v0.y + v0.z + v0.w + v1.x + v1.y + v1.z + v1.w;
    float ss = v0.x*v0.x + v0.y*v0.y + v0.z*v0.z + v0.w*v0.w
             + v1.x*v1.x + v1.y*v1.y + v1.z*v1.z + v1.w*v1.w;
    #pragma unroll
    for (int off = 1; off < 64; off <<= 1) {
        s  += __shfl_xor(s, off);
        ss += __shfl_xor(ss, off);
    }
    const float mean = s * (1.0f / C_);
    const float var  = ss * (1.0f / C_) - mean * mean;
    const float rs   = rsqrtf(var + 1e-5f);

    float4 g0 = *(const float4*)(gamma + lane * 8);
    float4 g1 = *(const float4*)(gamma + lane * 8 + 4);
    float4 b0 = *(const float4*)(beta  + lane * 8);
    float4 b1 = *(const float4*)(beta  + lane * 8 + 4);

    float o0 = (v0.x - mean) * rs * g0.x + b0.x;
    float o1 = (v0.y - mean) * rs * g0.y + b0.y;
    float o2 = (v0.z - mean) * rs * g0.z + b0.z;
    float o3 = (v0.w - mean) * rs * g0.w + b0.w;
    float o4 = (v1.x - mean) * rs * g1.x + b1.x;
    float o5 = (v1.y - mean) * rs * g1.y + b1.y;
    float o6 = (v1.z - mean) * rs * g1.z + b1.z;
    float o7 = (v1.w - mean) * rs * g1.w + b1.w;

    uint4 pk;
    pk.x = pack2(o0, o1);
    pk.y = pack2(o2, o3);
    pk.z = pack2(o4, o5);
    pk.w = pack2(o6, o7);
    *(uint4*)(y + (size_t)row * C_ + lane * 8) = pk;
}

// ---------------------------------------------------------------------------
// bf16 MFMA NT GEMM (m97 structure): C[m,n] = sum_k A[m,k]*Bw[n,k]
// A: [M,K] bf16 rm, Bw: [N,K] bf16 rm. 128x128 tile, BK=32, 4 waves,
// global_load_lds width=16, mfma_f32_16x16x32_bf16, acc 4x4 frags/wave.
// 1D grid with bijective XCD swizzle (requires gridDim.x % 8 == 0).
// MODE 0: fp32 plain store
// MODE 1: fp32 store at rolled row (+SHIFT) with residual add (resid = x)
// MODE 2: bias + exact GELU -> bf16 store
// MODE 3: bias + residual add -> fp32 store (resid may alias Cout, same idx)
// MODE 4: bf16 plain store
// ---------------------------------------------------------------------------
#define GBM 128
#define GBN 128
#define GBK 32

template <int MODE>
__global__ __launch_bounds__(256)
void gemm_bf16(const unsigned short* __restrict__ A, const unsigned short* __restrict__ Bw,
               void* __restrict__ Cout, int M, int N, int K, int nbx,
               const float* __restrict__ bias, const float* __restrict__ resid) {
    __shared__ __align__(16) unsigned short As[GBM][GBK];   // 8 KB
    __shared__ __align__(16) unsigned short Bs[GBN][GBK];   // 8 KB

    // XCD-aware bijective remap: XCD x owns a contiguous chunk of tile ids,
    // so the nbx col-blocks sharing an A-panel land on one XCD's L2.
    const int nwg = gridDim.x;
    int wg = blockIdx.x;
    wg = (wg & 7) * (nwg >> 3) + (wg >> 3);
    const int bx = wg % nbx;           // along N
    const int by = wg / nbx;           // along M

    const int t    = threadIdx.x;
    const int lane = t & 63;
    const int wid  = t >> 6;           // 0..3
    const int wr   = wid >> 1;         // wave row 0..1
    const int wc   = wid & 1;          // wave col 0..1

    // staging: wave wid stages rows [wid*32, wid*32+32) of both tiles,
    // as two 1KB chunks (16 rows each). lane: row += lane/4, k = (lane&3)*8.
    const int st_row = lane >> 2;
    const int st_k   = (lane & 3) * 8;

    const unsigned short* Ap0 = A  + ((size_t)(by * GBM + wid * 32 + st_row)) * K + st_k;
    const unsigned short* Ap1 = Ap0 + (size_t)16 * K;
    const unsigned short* Bp0 = Bw + ((size_t)(bx * GBN + wid * 32 + st_row)) * K + st_k;
    const unsigned short* Bp1 = Bp0 + (size_t)16 * K;

    f32x4 acc[4][4];
    #pragma unroll
    for (int i = 0; i < 4; ++i)
        #pragma unroll
        for (int j = 0; j < 4; ++j)
            acc[i][j] = (f32x4){0.f, 0.f, 0.f, 0.f};

    const int frow = lane & 15;          // fragment row/col within 16
    const int kk   = (lane >> 4) * 8;    // k-offset of this lane's 8 elems

    for (int k0 = 0; k0 < K; k0 += GBK) {
        __syncthreads();   // all waves done reading LDS from previous step
        gload_lds16(Ap0 + k0, &As[wid * 32     ][0]);
        gload_lds16(Ap1 + k0, &As[wid * 32 + 16][0]);
        gload_lds16(Bp0 + k0, &Bs[wid * 32     ][0]);
        gload_lds16(Bp1 + k0, &Bs[wid * 32 + 16][0]);
        __syncthreads();   // drains vmcnt -> staged tile visible

        bf16x8 af[4], bfr[4];
        #pragma unroll
        for (int mi = 0; mi < 4; ++mi)
            af[mi] = *(const bf16x8*)&As[wr * 64 + mi * 16 + frow][kk];
        #pragma unroll
        for (int ni = 0; ni < 4; ++ni)
            bfr[ni] = *(const bf16x8*)&Bs[wc * 64 + ni * 16 + frow][kk];
        #pragma unroll
        for (int mi = 0; mi < 4; ++mi)
            #pragma unroll
            for (int ni = 0; ni < 4; ++ni)
                acc[mi][ni] = __builtin_amdgcn_mfma_f32_16x16x32_bf16(
                    af[mi], bfr[ni], acc[mi][ni], 0, 0, 0);
    }

    // epilogue: D[row][col], col = lane&15, row = (lane>>4)*4 + r  (m89-verified)
    const int col0 = bx * GBN + wc * 64 + (lane & 15);
    const int row0 = by * GBM + wr * 64 + (lane >> 4) * 4;
    #pragma unroll
    for (int mi = 0; mi < 4; ++mi) {
        #pragma unroll
        for (int r = 0; r < 4; ++r) {
            const int m = row0 + mi * 16 + r;
            #pragma unroll
            for (int ni = 0; ni < 4; ++ni) {
                const int n = col0 + ni * 16;
                float v = acc[mi][ni][r];
                if (MODE == 0) {
                    ((float*)Cout)[(size_t)m * N + n] = v;
                } else if (MODE == 1) {
                    const int b  = m >> 12;
                    const int lp = m & (L_ - 1);
                    const int l  = (lp + SHIFT_) & (L_ - 1);
                    const size_t o = (size_t)((b << 12) + l) * N + n;
                    ((float*)Cout)[o] = v + resid[o];
                } else if (MODE == 2) {
                    ((unsigned short*)Cout)[(size_t)m * N + n] = f2bf(gelu_exact(v + bias[n]));
                } else if (MODE == 3) {
                    const size_t o = (size_t)m * N + n;
                    ((float*)Cout)[o] = v + bias[n] + resid[o];
                } else { // MODE 4
                    ((unsigned short*)Cout)[(size_t)m * N + n] = f2bf(v);
                }
            }
        }
    }
}

// ---------------------------------------------------------------------------
// Windowed attention: one block per (window-batch wm, head h).
// qkv layout: [B*nW*WS, 1536] bf16; q at col h*64, k at 512+h*64, v at 1024+h*64.
// Unpacks to fp32 LDS; all softmax math fp32.
// Writes probs fp32 to attn_out [B*nW, NH, WS, WS] and bf16 ctx [M, C].
// ---------------------------------------------------------------------------
__device__ __forceinline__ void unpack8(uint4 u, float* dst) {
    dst[0] = b2f_lo(u.x); dst[1] = b2f_hi(u.x);
    dst[2] = b2f_lo(u.y); dst[3] = b2f_hi(u.y);
    dst[4] = b2f_lo(u.z); dst[5] = b2f_hi(u.z);
    dst[6] = b2f_lo(u.w); dst[7] = b2f_hi(u.w);
}

__global__ __launch_bounds__(256)
void attn_kernel(const unsigned short* __restrict__ qkv, const float* __restrict__ rel,
                 float* __restrict__ attn_out, unsigned short* __restrict__ ctx) {
    __shared__ float qs[64][65];
    __shared__ float ks[64][65];
    __shared__ float vs[64][65];

    const int wm = blockIdx.x >> 3;         // window-batch index [0, B*nW)
    const int h  = blockIdx.x & 7;
    const int w  = wm & (NW_ - 1);          // window index within batch
    const int t  = threadIdx.x;
    const int i  = t >> 2;                  // q row owned
    const int c4 = (t & 3) * 16;            // column chunk for staging

    {
        const size_t base = ((size_t)wm * WS_ + i) * 1536 + h * DK_ + c4;
        uint4 qa = *(const uint4*)(qkv + base);
        uint4 qb = *(const uint4*)(qkv + base + 8);
        uint4 ka = *(const uint4*)(qkv + base + 512);
        uint4 kb = *(const uint4*)(qkv + base + 520);
        uint4 va = *(const uint4*)(qkv + base + 1024);
        uint4 vb = *(const uint4*)(qkv + base + 1032);
        unpack8(qa, &qs[i][c4]);     unpack8(qb, &qs[i][c4 + 8]);
        unpack8(ka, &ks[i][c4]);     unpack8(kb, &ks[i][c4 + 8]);
        unpack8(va, &vs[i][c4]);     unpack8(vb, &vs[i][c4 + 8]);
    }
    __syncthreads();

    const int j0 = (t & 3) * 16;            // this thread's 16 key columns
    float s[16];
    #pragma unroll
    for (int jj = 0; jj < 16; ++jj) s[jj] = 0.0f;

    for (int d = 0; d < 64; ++d) {
        const float qv = qs[i][d];
        #pragma unroll
        for (int jj = 0; jj < 16; ++jj)
            s[jj] = fmaf(qv, ks[j0 + jj][d], s[jj]);
    }

    #pragma unroll
    for (int jj = 0; jj < 16; ++jj) {
        const int j = j0 + jj;
        float bias = rel[(i - j + WS_ - 1) * NH_ + h];
        float mk = 0.0f;
        if (w == NW_ - 1 && ((i < 32) != (j < 32))) mk = -100.0f;
        s[jj] = s[jj] * 0.125f + bias + mk;
    }

    float mx = s[0];
    #pragma unroll
    for (int jj = 1; jj < 16; ++jj) mx = fmaxf(mx, s[jj]);
    mx = fmaxf(mx, __shfl_xor(mx, 1));
    mx = fmaxf(mx, __shfl_xor(mx, 2));
    float sum = 0.0f;
    #pragma unroll
    for (int jj = 0; jj < 16; ++jj) {
        s[jj] = expf(s[jj] - mx);
        sum += s[jj];
    }
    sum += __shfl_xor(sum, 1);
    sum += __shfl_xor(sum, 2);
    const float inv = 1.0f / sum;
    #pragma unroll
    for (int jj = 0; jj < 16; ++jj) s[jj] *= inv;

    // attention probabilities (validated output)
    {
        float* ar = attn_out + (((size_t)wm * NH_ + h) * WS_ + i) * WS_ + j0;
        #pragma unroll
        for (int u = 0; u < 16; u += 4) {
            float4 r;
            r.x = s[u + 0]; r.y = s[u + 1]; r.z = s[u + 2]; r.w = s[u + 3];
            *(float4*)(ar + u) = r;
        }
    }

    // ctx[i, d] = sum_j P[i,j] * v[j,d]; butterfly over the 4 lanes of row i.
    #pragma unroll
    for (int dc = 0; dc < 4; ++dc) {
        float part[16];
        #pragma unroll
        for (int dd = 0; dd < 16; ++dd) part[dd] = 0.0f;
        #pragma unroll
        for (int jj = 0; jj < 16; ++jj) {
            const float pv = s[jj];
            #pragma unroll
            for (int dd = 0; dd < 16; ++dd)
                part[dd] = fmaf(pv, vs[j0 + jj][dc * 16 + dd], part[dd]);
        }
        #pragma unroll
        for (int dd = 0; dd < 16; ++dd) {
            part[dd] += __shfl_xor(part[dd], 1);
            part[dd] += __shfl_xor(part[dd], 2);
        }
        if ((t & 3) == dc) {
            unsigned short* cr = ctx + ((size_t)wm * WS_ + i) * C_ + h * DK_ + dc * 16;
            uint4 o0, o1;
            o0.x = pack2(part[0],  part[1]);
            o0.y = pack2(part[2],  part[3]);
            o0.z = pack2(part[4],  part[5]);
            o0.w = pack2(part[6],  part[7]);
            o1.x = pack2(part[8],  part[9]);
            o1.y = pack2(part[10], part[11]);
            o1.z = pack2(part[12], part[13]);
            o1.w = pack2(part[14], part[15]);
            *(uint4*)(cr)     = o0;
            *(uint4*)(cr + 8) = o1;
        }
    }
}

// ---------------------------------------------------------------------------
// Depthwise conv (k=3 along L, zero pad) + in-FFN residual + exact GELU.
// bf16 in (g), bf16 out. 8 elems/thread.
// ---------------------------------------------------------------------------
__global__ __launch_bounds__(256)
void dwconv_gelu_kernel(const unsigned short* __restrict__ g, const float* __restrict__ w,
                        const float* __restrict__ bias, unsigned short* __restrict__ out) {
    const size_t idx = (size_t)blockIdx.x * blockDim.x + threadIdx.x;
    const size_t e   = idx * 8;
    const int c   = (int)(e & (HID_ - 1));
    const size_t row = e >> 11;            // / HID
    const int l   = (int)(row & (L_ - 1));

    uint4 cv = *(const uint4*)(g + e);
    uint4 lv = (l > 0)      ? *(const uint4*)(g + e - HID_) : make_uint4(0,0,0,0);
    uint4 rv = (l < L_ - 1) ? *(const uint4*)(g + e + HID_) : make_uint4(0,0,0,0);

    float cc[8], ll[8], rr[8];
    unpack8(cv, cc); unpack8(lv, ll); unpack8(rv, rr);

    float res[8];
    #pragma unroll
    for (int u = 0; u < 8; ++u) {
        const float* wr = w + (size_t)(c + u) * 3;
        float dw = ll[u] * wr[0] + cc[u] * wr[1] + rr[u] * wr[2] + bias[c + u];
        res[u] = gelu_exact(dw + cc[u]);
    }
    uint4 o;
    o.x = pack2(res[0], res[1]);
    o.y = pack2(res[2], res[3]);
    o.z = pack2(res[4], res[5]);
    o.w = pack2(res[6], res[7]);
    *(uint4*)(out + e) = o;
}

// ---------------------------------------------------------------------------
// Launch
// ---------------------------------------------------------------------------
extern "C" void kernel_launch(void* const* d_in, const int* in_sizes, int n_in,
                              void* d_out, int out_size, void* d_ws, size_t ws_size,
                              hipStream_t stream) {
    (void)in_sizes; (void)n_in; (void)out_size;

    const float* x     = (const float*)d_in[0];
    const float* ln1_g = (const float*)d_in[1];
    const float* ln1_b = (const float*)d_in[2];
    const float* w_q   = (const float*)d_in[3];
    const float* w_k   = (const float*)d_in[4];
    const float* w_v   = (const float*)d_in[5];
    const float* w_o   = (const float*)d_in[6];
    const float* rel   = (const float*)d_in[7];
    const float* ln2_g = (const float*)d_in[8];
    const float* ln2_b = (const float*)d_in[9];
    const float* c1_w  = (const float*)d_in[10];
    const float* c1_b  = (const float*)d_in[11];
    const float* c2_w  = (const float*)d_in[12];
    const float* c2_b  = (const float*)d_in[13];
    const float* c3_w  = (const float*)d_in[14];
    const float* c3_b  = (const float*)d_in[15];

    const int M = B_ * L_;                       // 131072
    const size_t SZ = (size_t)M * C_;            // 67,108,864

    // Workspace layout (shorts), exact-overlay reuse. Total = M*4096*2 B
    // (1 GiB) + 6.5 MB weights.
    //   [p0] qkv  bf16 [M][1536]   (dead after attn)
    //   [p1] ctxb bf16 [M][512]    (dead after o-proj)    } p0+p1 = gbuf [M][2048]
    //   [p2] hln  bf16 [M][512]    (dead after c1)        } p2+p3 = f2   [M][2048]
    //   [p3] xtra bf16 [M][1536]
    const size_t NEEDED = (size_t)M * 4096 * 2 +
                          ((size_t)1536 * 512 + 512 * 512 + (size_t)HID_ * 512 +
                           (size_t)512 * HID_) * 2;
    if (ws_size < NEEDED) return;   // graceful fail: output stays poisoned

    unsigned short* p0 = (unsigned short*)d_ws;
    unsigned short* qkv  = p0;                          // M*1536
    unsigned short* ctxb = p0 + (size_t)M * 1536;       // M*512
    unsigned short* hln  = p0 + (size_t)M * 2048;       // M*512
    unsigned short* gbuf = p0;                          // M*2048 (overlays qkv+ctxb)
    unsigned short* f2   = hln;                         // M*2048 (overlays hln+xtra)
    unsigned short* wq_  = p0 + (size_t)M * 4096;
    unsigned short* wqkv = wq_;                         // 1536*512
    unsigned short* wob  = wqkv + (size_t)1536 * 512;   // 512*512
    unsigned short* c1wb = wob  + (size_t)512 * 512;    // 2048*512
    unsigned short* c3wb = c1wb + (size_t)HID_ * 512;   // 512*2048

    float* out_main = (float*)d_out;
    float* out_attn = out_main + SZ;
    float* out1 = out_main;   // attention-branch output lives in d_out; c3 epilogue
                              // reads resid[o] and overwrites the same o (safe).

    // 0. weight conversions fp32 -> bf16 (wqkv = [w_q; w_k; w_v] rows)
    f2b_kernel<<<256,  256, 0, stream>>>(w_q,  wqkv,            65536);
    f2b_kernel<<<256,  256, 0, stream>>>(w_k,  wqkv + 262144,   65536);
    f2b_kernel<<<256,  256, 0, stream>>>(w_v,  wqkv + 524288,   65536);
    f2b_kernel<<<256,  256, 0, stream>>>(w_o,  wob,             65536);
    f2b_kernel<<<1024, 256, 0, stream>>>(c1_w, c1wb,            262144);
    f2b_kernel<<<1024, 256, 0, stream>>>(c3_w, c3wb,            262144);

    // 1. LN1 + roll(-SHIFT) -> bf16
    ln_kernel<<<M / 4, 256, 0, stream>>>(x, ln1_g, ln1_b, hln, SHIFT_);

    // 2. fused QKV projection: [M,512] x [1536,512]^T -> bf16 qkv [M,1536]
    gemm_bf16<4><<<(1536 / GBN) * (M / GBM), 256, 0, stream>>>(
        hln, wqkv, qkv, M, 1536, C_, 1536 / GBN, nullptr, nullptr);

    // 3. windowed attention -> attn probs (fp32 out) + bf16 ctx
    attn_kernel<<<B_ * NW_ * NH_, 256, 0, stream>>>(qkv, rel, out_attn, ctxb);

    // 4. output projection + roll(+SHIFT) + residual(x) -> fp32 out1 (in d_out)
    gemm_bf16<1><<<(C_ / GBN) * (M / GBM), 256, 0, stream>>>(
        ctxb, wob, out1, M, C_, C_, C_ / GBN, nullptr, x);

    // 5. LN2 -> bf16 (qkv/ctxb dead from here)
    ln_kernel<<<M / 4, 256, 0, stream>>>(out1, ln2_g, ln2_b, hln, 0);

    // 6. c1 + bias + GELU -> bf16 gbuf (overlays qkv+ctxb)
    gemm_bf16<2><<<(HID_ / GBN) * (M / GBM), 256, 0, stream>>>(
        hln, c1wb, gbuf, M, HID_, C_, HID_ / GBN, c1_b, nullptr);

    // 7. depthwise conv + residual + GELU -> bf16 f2 (overlays hln+xtra; hln dead)
    dwconv_gelu_kernel<<<(unsigned)(((size_t)M * HID_ / 8) / 256), 256, 0, stream>>>(
        gbuf, c2_w, c2_b, f2);

    // 8. c3 + bias + residual(out1) -> final fp32 output (in-place in d_out)
    gemm_bf16<3><<<(C_ / GBN) * (M / GBM), 256, 0, stream>>>(
        f2, c3wb, out_main, M, C_, HID_, C_ / GBN, c3_b, out1);
}